// Round 1
// 591.835 us; speedup vs baseline: 1.1758x; 1.1758x over previous
//
#include <hip/hip_runtime.h>

#define IMG  262144
#define NPAT 4096

// ws layout (float offsets)
#define OFF_C9   0                       // 243 weights + bias at [243]
#define OFF_W    256                     // Wt[q][j], 4096 floats
#define OFF_G    4352                    // border-corr G[9][147] + Gb[9] = 1332 floats (pad 1344)
#define OFF_INI  5696                    // ini_img [4][512][512]
#define OFF_FMAP (OFF_INI + 4*IMG)       // feamap  [4][512][512]
#define OFF_V    (OFF_FMAP + 4*IMG)      // 4 ushort arrays of [4][4096][64]: imgH imgL feaH feaL

typedef short v8s __attribute__((ext_vector_type(8)));
typedef float v4f __attribute__((ext_vector_type(4)));

__device__ inline unsigned short f2bf(float x) {
  unsigned u = __float_as_uint(x);
  u = u + 0x7FFF + ((u >> 16) & 1);
  return (unsigned short)(u >> 16);
}
__device__ inline float bf2f(unsigned short h) {
  return __uint_as_float(((unsigned)h) << 16);
}

// ---------------- Kernel P: feamap (1x1 conv + /4) fused with weight composition ----------------
// blocks 0..1023   : feamap pixels (memory-bound, hides the compose work)
// blocks 1024..1039: Wt[q][j] composition (w2@w1)
// block  1040      : composite 9x9 conv weights + bias
// blocks 1041..1046: border-correction weights G[9][147], Gb[9]
__global__ __launch_bounds__(256) void k_prep(
    const float* __restrict__ fea,   const float* __restrict__ wfea,
    const float* __restrict__ bfea,
    const float* __restrict__ w1img, const float* __restrict__ b1img,
    const float* __restrict__ w2img, const float* __restrict__ b2img,
    const float* __restrict__ w1,    const float* __restrict__ w2,
    float* __restrict__ ws) {
  int bid = blockIdx.x, tid = threadIdx.x;
  if (bid < 1024) {
    int pix = bid * 1024 + tid * 4;
    int b = pix >> 18;
    int rem = pix & (IMG - 1);
    const float* src = fea + (size_t)(b * 64) * IMG + rem;
    v4f acc = {0.f, 0.f, 0.f, 0.f};
    #pragma unroll 8
    for (int c = 0; c < 64; ++c) {
      float w = wfea[c];
      v4f v = __builtin_nontemporal_load((const v4f*)(src + (size_t)c * IMG));
      acc += w * v;                       // fea is read-once: keep it out of L2
    }
    float bb = bfea[0];
    acc = (acc + bb) * 0.25f;
    *(v4f*)(ws + OFF_FMAP + pix) = acc;   // fmap is reused by k_trans: normal store
    return;
  }
  if (bid < 1040) {
    // Wt[q][j] = sum_k w2[j,k]*w1[k,q]; wave-uniform j -> w2 row via s_load
    int j = (bid - 1024) * 4 + (tid >> 6), q = tid & 63;
    float acc = 0.f;
    for (int k = 0; k < 128; ++k) acc += w2[j * 128 + k] * w1[k * 64 + q];
    ws[OFF_W + q * 64 + j] = acc;
    return;
  }
  if (bid == 1040) {
    // combined 9x9 conv weights + bias
    if (tid < 243) {
      int i = tid / 81, r = tid % 81, dy = r / 9, dx = r % 9;
      float acc = 0.f;
      for (int m = 0; m < 64; ++m)
        for (int ky = 0; ky < 3; ++ky) {
          int k1y = dy - ky; if (k1y < 0 || k1y > 6) continue;
          for (int kx = 0; kx < 3; ++kx) {
            int k1x = dx - kx; if (k1x < 0 || k1x > 6) continue;
            acc += w2img[m * 9 + ky * 3 + kx] * w1img[(m * 3 + i) * 49 + k1y * 7 + k1x];
          }
        }
      ws[OFF_C9 + tid] = acc;
    } else if (tid == 243) {
      float acc = b2img[0];
      for (int m = 0; m < 64; ++m) {
        float s = 0.f;
        for (int k = 0; k < 9; ++k) s += w2img[m * 9 + k];
        acc += b1img[m] * s;
      }
      ws[OFF_C9 + 243] = acc;
    }
    return;
  }
  // border-correction weights: G[k2][i*49+k1] = sum_m w2[m,k2]*w1[m,i,k1]; Gb[k2] = sum_m w2[m,k2]*b1[m]
  int gidx = (bid - 1041) * 256 + tid;
  if (gidx < 1323) {
    int k2 = gidx / 147, t = gidx % 147;
    float acc = 0.f;
    for (int m = 0; m < 64; ++m) acc += w2img[m * 9 + k2] * w1img[m * 147 + t];
    ws[OFF_G + gidx] = acc;
  } else if (gidx < 1332) {
    int k2 = gidx - 1323;
    float acc = 0.f;
    for (int m = 0; m < 64; ++m) acc += w2img[m * 9 + k2] * b1img[m];
    ws[OFF_G + gidx] = acc;
  }
}

// ---------------- Kernel B1: composite 9x9 conv (tile 16x64, 4 out/thread) ----------------
__global__ __launch_bounds__(256) void k_conv9(const float* __restrict__ x,
                                               const float* __restrict__ ws,
                                               float* __restrict__ ini) {
  __shared__ float sIn[3][24][72];
  int bid = blockIdx.x, tid = threadIdx.x;
  int b = bid >> 8, t = bid & 255;
  int ty0 = (t >> 3) << 4, tx0 = (t & 7) << 6;
  // stage 3ch x 24 x 72 halo tile
  for (int idx = tid; idx < 3 * 24 * 72; idx += 256) {
    int c = idx / 1728, r = (idx % 1728) / 72, cc = idx % 72;
    int gy = ty0 + r - 4, gx = tx0 + cc - 4;
    float v = 0.f;
    if ((unsigned)gy < 512u && (unsigned)gx < 512u)
      v = x[(b * 3 + c) * IMG + gy * 512 + gx];
    sIn[c][r][cc] = v;
  }
  __syncthreads();
  const float* Cw = ws + OFF_C9;   // uniform -> scalar loads
  int ty = tid >> 4, tx = (tid & 15) << 2;
  float bc = Cw[243];
  float a0 = bc, a1 = bc, a2 = bc, a3 = bc;
  #pragma unroll
  for (int i = 0; i < 3; ++i)
    #pragma unroll
    for (int dy = 0; dy < 9; ++dy) {
      const float* rowp = &sIn[i][ty + dy][tx];
      float4 r0 = *(const float4*)rowp;
      float4 r1 = *(const float4*)(rowp + 4);
      float4 r2 = *(const float4*)(rowp + 8);
      float tt[12] = {r0.x, r0.y, r0.z, r0.w, r1.x, r1.y, r1.z, r1.w,
                      r2.x, r2.y, r2.z, r2.w};
      #pragma unroll
      for (int dx = 0; dx < 9; ++dx) {
        float w = Cw[i * 81 + dy * 9 + dx];
        a0 += w * tt[dx];     a1 += w * tt[dx + 1];
        a2 += w * tt[dx + 2]; a3 += w * tt[dx + 3];
      }
    }
  float4 o = {a0, a1, a2, a3};
  *(float4*)&ini[b * IMG + (ty0 + ty) * 512 + tx0 + tx] = o;
}

// ---------------- Kernel B1b: border-ring correction (precomposed G, 1 thread/pixel) ----------------
__global__ __launch_bounds__(256) void k_ring(const float* __restrict__ x,
                                              const float* __restrict__ ws,
                                              float* __restrict__ ini) {
  int gid = blockIdx.x * 256 + threadIdx.x;
  if (gid >= 4 * 2044) return;
  int b = gid / 2044;
  int r = gid % 2044;
  int py, px;
  if (r < 512)       { py = 0;            px = r;        }
  else if (r < 1024) { py = 511;          px = r - 512;  }
  else if (r < 1534) { py = r - 1024 + 1; px = 0;        }
  else               { py = r - 1534 + 1; px = 511;      }
  const float* G  = ws + OFF_G;
  const float* Gb = G + 1323;
  const float* xb = x + (size_t)(b * 3) * IMG;
  float corr = 0.f;
  for (int k2y = 0; k2y < 3; ++k2y) {
    int qy = py + k2y - 1;
    for (int k2x = 0; k2x < 3; ++k2x) {
      int qx = px + k2x - 1;
      if (!((unsigned)qy >= 512u || (unsigned)qx >= 512u)) continue;  // only pad taps
      int k2 = k2y * 3 + k2x;
      float acc = Gb[k2];
      for (int i = 0; i < 3; ++i)
        for (int k1y = 0; k1y < 7; ++k1y) {
          int xy = qy + k1y - 3;
          if ((unsigned)xy >= 512u) continue;
          const float* xrow = xb + i * IMG + xy * 512;
          const float* Grow = G + k2 * 147 + i * 49 + k1y * 7;
          for (int k1x = 0; k1x < 7; ++k1x) {
            int xx = qx + k1x - 3;
            if ((unsigned)xx >= 512u) continue;
            acc += Grow[k1x] * xrow[xx];
          }
        }
      corr += acc;
    }
  }
  ini[b * IMG + py * 512 + px] -= corr;
}

// ---------------- Kernel C: unfold + fused linear + relu + bf16 hi/lo split ----------------
__global__ __launch_bounds__(256) void k_trans(float* __restrict__ ws) {
  __shared__ float Us[64][68];
  int bid = blockIdx.x, tid = threadIdx.x;
  int s = bid >> 8, b = (bid >> 6) & 3, py = bid & 63;
  const float* src = ws + (s ? OFF_FMAP : OFF_INI) + b * IMG + py * 8 * 512;
  unsigned short* Vh = (unsigned short*)(ws + OFF_V) + (s ? 2097152 : 0) + b * NPAT * 64;
  unsigned short* Vl = Vh + 1048576;
  // stage 8 rows x 512 cols -> Us[px][q]  (q = r*8+c)
  #pragma unroll
  for (int i = 0; i < 4; ++i) {
    int idx = tid + 256 * i;          // 0..1023 float4 slots
    int row = idx >> 7;               // 0..7
    int c4  = (idx & 127) * 4;        // 0..508
    float4 v = *(const float4*)(src + row * 512 + c4);
    int px = c4 >> 3, c = c4 & 7;
    *(float4*)&Us[px][row * 8 + c] = v;
  }
  int j = tid & 63, wid = tid >> 6;
  float wc[64];
  #pragma unroll
  for (int q = 0; q < 64; ++q) wc[q] = ws[OFF_W + q * 64 + j];
  __syncthreads();
  #pragma unroll
  for (int i = 0; i < 16; ++i) {
    int lp = wid * 16 + i;
    float acc = 0.f;
    #pragma unroll
    for (int q4 = 0; q4 < 16; ++q4) {
      float4 u = *(const float4*)&Us[lp][q4 * 4];
      acc += u.x * wc[4*q4] + u.y * wc[4*q4+1] + u.z * wc[4*q4+2] + u.w * wc[4*q4+3];
    }
    acc = fmaxf(acc, 0.f);
    unsigned short h = f2bf(acc);
    unsigned short lo = f2bf(acc - bf2f(h));
    int lg = py * 64 + lp;
    Vh[lg * 64 + j] = h;
    Vl[lg * 64 + j] = lo;
  }
}

// ---------------- Kernel D: att = v_img @ v_fea^T / 64  (bf16-split MFMA) ----------------
__global__ __launch_bounds__(256) void k_att(const float* __restrict__ ws,
                                             float* __restrict__ out) {
  __shared__ unsigned short lds[4][128][64];  // Ah Al Bh Bl, XOR-swizzled 16B segs
  // bijective XCD swizzle: 4096 blocks, 8 XCDs -> each XCD works a contiguous
  // 512-tile chunk (A 512KB + B 1MB working set fits the 4MB per-XCD L2)
  int bid0 = blockIdx.x;
  int bid = (bid0 & 7) * 512 + (bid0 >> 3);
  int tid = threadIdx.x;
  int b = bid >> 10, t = bid & 1023;
  int l0 = (t >> 5) << 7, m0 = (t & 31) << 7;
  const unsigned short* V = (const unsigned short*)(ws + OFF_V);
  const unsigned short* pA_h = V + (b * NPAT + l0) * 64;
  const unsigned short* pA_l = V + 1048576 + (b * NPAT + l0) * 64;
  const unsigned short* pB_h = V + 2097152 + (b * NPAT + m0) * 64;
  const unsigned short* pB_l = V + 3145728 + (b * NPAT + m0) * 64;
  #pragma unroll
  for (int i = 0; i < 4; ++i) {
    int idx = tid + 256 * i;            // 0..1023: row(128) x seg(8)
    int row = idx >> 3, sg = idx & 7;
    int p = (sg ^ (row & 7)) * 8;
    *(uint4*)&lds[0][row][p] = *(const uint4*)(pA_h + row * 64 + sg * 8);
    *(uint4*)&lds[1][row][p] = *(const uint4*)(pA_l + row * 64 + sg * 8);
    *(uint4*)&lds[2][row][p] = *(const uint4*)(pB_h + row * 64 + sg * 8);
    *(uint4*)&lds[3][row][p] = *(const uint4*)(pB_l + row * 64 + sg * 8);
  }
  __syncthreads();
  int lane = tid & 63, wid = tid >> 6;
  int wm = (wid & 1) << 6, wn = (wid >> 1) << 6;
  int mlo = lane & 15, quad = lane >> 4;
  v4f acc[4][4] = {};
  #pragma unroll
  for (int kh = 0; kh < 2; ++kh) {
    int sL = quad + 4 * kh;
    v8s ah[4], al[4], bh[4], bl[4];
    #pragma unroll
    for (int mi = 0; mi < 4; ++mi) {
      int r = wm + mi * 16 + mlo;
      int p = (sL ^ (r & 7)) * 8;
      ah[mi] = *(const v8s*)&lds[0][r][p];
      al[mi] = *(const v8s*)&lds[1][r][p];
    }
    #pragma unroll
    for (int ni = 0; ni < 4; ++ni) {
      int r = wn + ni * 16 + mlo;
      int p = (sL ^ (r & 7)) * 8;
      bh[ni] = *(const v8s*)&lds[2][r][p];
      bl[ni] = *(const v8s*)&lds[3][r][p];
    }
    #pragma unroll
    for (int mi = 0; mi < 4; ++mi)
      #pragma unroll
      for (int ni = 0; ni < 4; ++ni) {
        acc[mi][ni] = __builtin_amdgcn_mfma_f32_16x16x32_bf16(ah[mi], bh[ni], acc[mi][ni], 0, 0, 0);
        acc[mi][ni] = __builtin_amdgcn_mfma_f32_16x16x32_bf16(ah[mi], bl[ni], acc[mi][ni], 0, 0, 0);
        acc[mi][ni] = __builtin_amdgcn_mfma_f32_16x16x32_bf16(al[mi], bh[ni], acc[mi][ni], 0, 0, 0);
      }
  }
  float* o = out + (size_t)b * 16777216;
  #pragma unroll
  for (int mi = 0; mi < 4; ++mi)
    #pragma unroll
    for (int ni = 0; ni < 4; ++ni) {
      int col = m0 + wn + ni * 16 + mlo;
      #pragma unroll
      for (int rr = 0; rr < 4; ++rr) {
        int row = l0 + wm + mi * 16 + quad * 4 + rr;
        // output is write-once/streaming: nontemporal keeps V panels resident in L2
        __builtin_nontemporal_store(acc[mi][ni][rr] * 0.015625f,
                                    o + (size_t)row * 4096 + col);
      }
    }
}

extern "C" void kernel_launch(void* const* d_in, const int* in_sizes, int n_in,
                              void* d_out, int out_size, void* d_ws, size_t ws_size,
                              hipStream_t stream) {
  const float* x      = (const float*)d_in[0];
  const float* fea    = (const float*)d_in[1];
  const float* w_img1 = (const float*)d_in[2];
  const float* b_img1 = (const float*)d_in[3];
  const float* w_img2 = (const float*)d_in[4];
  const float* b_img2 = (const float*)d_in[5];
  const float* w_fea  = (const float*)d_in[6];
  const float* b_fea  = (const float*)d_in[7];
  const float* w1     = (const float*)d_in[8];
  const float* w2     = (const float*)d_in[9];
  float* ws  = (float*)d_ws;
  float* out = (float*)d_out;

  k_prep  <<<1047, 256, 0, stream>>>(fea, w_fea, b_fea, w_img1, b_img1,
                                     w_img2, b_img2, w1, w2, ws);
  k_conv9 <<<1024, 256, 0, stream>>>(x, ws, ws + OFF_INI);
  k_ring  <<<32,   256, 0, stream>>>(x, ws, ws + OFF_INI);
  k_trans <<<512,  256, 0, stream>>>(ws);
  k_att   <<<4096, 256, 0, stream>>>(ws, out);
}